// Round 2
// baseline (103.290 us; speedup 1.0000x reference)
//
#include <hip/hip_runtime.h>

// Problem constants (reference: B=256, L=512, N=4)
constexpr int B = 256;
constexpr int L = 512;
constexpr int N = 4;
constexpr int JSTRIDE = 8;   // j-loop split across blockIdx.y for load balance

#define MARGIN 1e-3f

// ---------------------------------------------------------------------------
// Main kernel: block = (i, jc). Each block holds row i's data in registers
// (each of 256 threads owns l = t and l = t+256, i.e. float4 over n=0..3),
// then loops j = i+1+jc, j += JSTRIDE, streaming row j from cache.
// Accumulates per-feature loss-sum and mask-count, reduces per block,
// atomically adds (as double) into the 8-slot workspace accumulator.
// Masks are int32 (0/1), 4 bytes per element.
// ---------------------------------------------------------------------------
__global__ __launch_bounds__(256) void pair_bce_kernel(
    const float* __restrict__ preds,
    const float* __restrict__ targets,
    const int*   __restrict__ masks,
    double* __restrict__ acc)   // acc[0..3] = loss_sum[n], acc[4..7] = mask_sum[n]
{
    const int i  = blockIdx.x;      // 0 .. B-2
    const int jc = blockIdx.y;      // 0 .. JSTRIDE-1
    const int t  = threadIdx.x;     // 0 .. 255

    const int l0 = t;
    const int l1 = t + 256;

    // i-row data in registers (coalesced float4 / int4 loads)
    const float4 pi0 = *(const float4*)(preds   + (size_t)(i * L + l0) * N);
    const float4 pi1 = *(const float4*)(preds   + (size_t)(i * L + l1) * N);
    const float4 ti0 = *(const float4*)(targets + (size_t)(i * L + l0) * N);
    const float4 ti1 = *(const float4*)(targets + (size_t)(i * L + l1) * N);
    const int4   mi0 = *(const int4*)(masks     + (size_t)(i * L + l0) * N);
    const int4   mi1 = *(const int4*)(masks     + (size_t)(i * L + l1) * N);

    float loss[4] = {0.f, 0.f, 0.f, 0.f};
    float cnt[4]  = {0.f, 0.f, 0.f, 0.f};

// Branchless per-element BCE-with-logits, masked accumulate
#define DO_ELEM(nn, PI, PJ, TI, TJ, MI, MJ)                                    \
    {                                                                          \
        const float m  = ((MI) && (MJ)) ? 1.0f : 0.0f;                         \
        const float x  = (PI) - (PJ);                                          \
        const float tg = (((TI) - (TJ)) > MARGIN) ? 1.0f : 0.0f;               \
        const float ax = fabsf(x);                                             \
        const float sp = __logf(1.0f + __expf(-ax));                           \
        const float bce = fmaxf(x, 0.0f) - x * tg + sp;                        \
        loss[nn] += m * bce;                                                   \
        cnt[nn]  += m;                                                         \
    }

    for (int j = i + 1 + jc; j < B; j += JSTRIDE) {
        const float4 pj0 = *(const float4*)(preds   + (size_t)(j * L + l0) * N);
        const float4 pj1 = *(const float4*)(preds   + (size_t)(j * L + l1) * N);
        const float4 tj0 = *(const float4*)(targets + (size_t)(j * L + l0) * N);
        const float4 tj1 = *(const float4*)(targets + (size_t)(j * L + l1) * N);
        const int4   mj0 = *(const int4*)(masks     + (size_t)(j * L + l0) * N);
        const int4   mj1 = *(const int4*)(masks     + (size_t)(j * L + l1) * N);

        DO_ELEM(0, pi0.x, pj0.x, ti0.x, tj0.x, mi0.x, mj0.x);
        DO_ELEM(1, pi0.y, pj0.y, ti0.y, tj0.y, mi0.y, mj0.y);
        DO_ELEM(2, pi0.z, pj0.z, ti0.z, tj0.z, mi0.z, mj0.z);
        DO_ELEM(3, pi0.w, pj0.w, ti0.w, tj0.w, mi0.w, mj0.w);

        DO_ELEM(0, pi1.x, pj1.x, ti1.x, tj1.x, mi1.x, mj1.x);
        DO_ELEM(1, pi1.y, pj1.y, ti1.y, tj1.y, mi1.y, mj1.y);
        DO_ELEM(2, pi1.z, pj1.z, ti1.z, tj1.z, mi1.z, mj1.z);
        DO_ELEM(3, pi1.w, pj1.w, ti1.w, tj1.w, mi1.w, mj1.w);
    }
#undef DO_ELEM

    // ---- block reduction: wave shuffle (64 lanes) -> LDS across 4 waves ----
    #pragma unroll
    for (int k = 0; k < 4; k++) {
        #pragma unroll
        for (int off = 32; off > 0; off >>= 1) {
            loss[k] += __shfl_down(loss[k], off, 64);
            cnt[k]  += __shfl_down(cnt[k],  off, 64);
        }
    }

    __shared__ float sred[4][8];    // [wave][value]
    const int wave = t >> 6;
    const int lane = t & 63;
    if (lane == 0) {
        #pragma unroll
        for (int k = 0; k < 4; k++) {
            sred[wave][k]     = loss[k];
            sred[wave][k + 4] = cnt[k];
        }
    }
    __syncthreads();

    if (t < 8) {
        const float v = sred[0][t] + sred[1][t] + sred[2][t] + sred[3][t];
        atomicAdd(&acc[t], (double)v);
    }
}

// ---------------------------------------------------------------------------
// Finalize: total = (1/N) * sum_n where(cnt>0, loss/(cnt+EPS), 0)
// ---------------------------------------------------------------------------
__global__ void finalize_kernel(const double* __restrict__ acc,
                                float* __restrict__ out)
{
    double total = 0.0;
    #pragma unroll
    for (int n = 0; n < 4; n++) {
        const double ls = acc[n];
        const double cs = acc[n + 4];
        total += (cs > 0.0) ? (ls / (cs + 1e-8)) : 0.0;
    }
    out[0] = (float)(total / (double)N);
}

extern "C" void kernel_launch(void* const* d_in, const int* in_sizes, int n_in,
                              void* d_out, int out_size, void* d_ws, size_t ws_size,
                              hipStream_t stream)
{
    const float* preds   = (const float*)d_in[0];
    const float* targets = (const float*)d_in[1];
    const int*   masks   = (const int*)d_in[2];   // jnp.bool_ arrives as int32
    float*  out = (float*)d_out;
    double* acc = (double*)d_ws;

    // Workspace is poisoned (0xAA) and never re-poisoned between replays:
    // zero our 8 accumulators every call.
    hipMemsetAsync(acc, 0, 8 * sizeof(double), stream);

    dim3 grid(B - 1, JSTRIDE);
    pair_bce_kernel<<<grid, 256, 0, stream>>>(preds, targets, masks, acc);
    finalize_kernel<<<1, 1, 0, stream>>>(acc, out);
}

// Round 4
// 73.341 us; speedup vs baseline: 1.4084x; 1.4084x over previous
//
#include <hip/hip_runtime.h>

// Problem constants (reference: B=256, L=512, N=4)
constexpr int B = 256;
constexpr int L = 512;            // threads cover L via l0=t, l1=t+256
constexpr int NPAIRS = (B * (B - 1)) / 2;   // 32640
constexpr int CHUNK  = 16;                  // pairs per block
constexpr int NBLK   = NPAIRS / CHUNK;      // 2040 blocks (exact)

#define MARGIN  1e-3f
#define LOG2E   1.4426950408889634f
#define LN2     0.6931471805599453

// ---- workspace layout (bytes) ----
// [0,    1024) : double slab[32][4]   loss partial sums (base-2 units), 32-way spread
// [1024, 1056) : double cnt4[4]       mask_sum per feature
// [4096, 4096+2MB)        : float psc[256*512*4]  preds * log2e
// [4096+2MB, +64KB)       : uchar pk[256][256]    packed masks (8 bits/thread-slot)
constexpr size_t OFF_SLAB = 0;
constexpr size_t OFF_CNT  = 1024;
constexpr size_t OFF_PSC  = 4096;
constexpr size_t OFF_PK   = 4096 + 2097152;

__device__ __forceinline__ int pair_start(int i) {  // # pairs before row i
    return (i * (511 - i)) / 2;                     // = 255*i - i*(i-1)/2
}

// ---------------------------------------------------------------------------
// Prep: blocks 0..511 scale preds by log2e; 512..767 pack masks to bytes;
// 768..775 compute mask_sum[n] = sum_l C(colcount,2) exactly.
// ---------------------------------------------------------------------------
__global__ __launch_bounds__(256) void prep_kernel(
    const float* __restrict__ preds,
    const int*   __restrict__ masks,
    float*        __restrict__ psc,
    unsigned char* __restrict__ pk,
    double*       __restrict__ cnt4)
{
    const int b = blockIdx.x;
    const int t = threadIdx.x;
    __shared__ float sred[256];

    if (b < 512) {
        const int idx = b * 256 + t;              // float4 index, 131072 total
        float4 v = ((const float4*)preds)[idx];
        v.x *= LOG2E; v.y *= LOG2E; v.z *= LOG2E; v.w *= LOG2E;
        ((float4*)psc)[idx] = v;
    } else if (b < 768) {
        const int r = b - 512;                    // mask row 0..255
        const int4 m0 = ((const int4*)masks)[r * 512 + t];
        const int4 m1 = ((const int4*)masks)[r * 512 + t + 256];
        const unsigned byte =
            (unsigned)m0.x | ((unsigned)m0.y << 1) | ((unsigned)m0.z << 2) |
            ((unsigned)m0.w << 3) | ((unsigned)m1.x << 4) | ((unsigned)m1.y << 5) |
            ((unsigned)m1.z << 6) | ((unsigned)m1.w << 7);
        pk[r * 256 + t] = (unsigned char)byte;
    } else {
        const int col = (b - 768) * 256 + t;      // 2048 columns = (l, n)
        int c = 0;
        #pragma unroll 8
        for (int r = 0; r < 256; ++r) c += masks[r * 2048 + col];
        sred[t] = (float)((c * (c - 1)) / 2);     // C(c,2), exact (<= 32640)
        __syncthreads();
        if (t < 4) {                              // n = col % 4 = t % 4
            float s = 0.f;
            for (int q = t; q < 256; q += 4) s += sred[q];
            atomicAdd(&cnt4[t], (double)s);
        }
    }
}

// ---------------------------------------------------------------------------
// Main: each block owns 16 contiguous pairs of the flat upper-triangle
// enumeration. i-row cached in registers; j advances sequentially.
// Loss accumulated in base-2 units (x ln2 applied at finalize).
// ---------------------------------------------------------------------------
__global__ __launch_bounds__(256) void pair_bce_kernel(
    const float* __restrict__ targets,
    const float* __restrict__ psc,          // scaled preds
    const unsigned char* __restrict__ pk,   // packed masks
    double* __restrict__ slab)              // [32][4]
{
    const int t = threadIdx.x;
    const int k0 = blockIdx.x * CHUNK;

    // unrank k0 -> (i, j)
    int i;
    {
        double d = (511.0 - sqrt(511.0 * 511.0 - 8.0 * (double)k0)) * 0.5;
        i = (int)d;
        while (pair_start(i + 1) <= k0) ++i;
        while (pair_start(i) > k0) --i;
    }
    int j = i + 1 + (k0 - pair_start(i));

    const float4* psc4 = (const float4*)psc;
    const float4* tgt4 = (const float4*)targets;

    float4 pi0, pi1, ti0, ti1;
    unsigned mi;
#define LOAD_I()                                                               \
    {                                                                          \
        pi0 = psc4[i * 512 + t];       pi1 = psc4[i * 512 + t + 256];          \
        ti0 = tgt4[i * 512 + t];       ti1 = tgt4[i * 512 + t + 256];          \
        mi  = pk[i * 256 + t];                                                 \
    }
    LOAD_I();

    float loss[4] = {0.f, 0.f, 0.f, 0.f};

#define ELEM(nn, bit, UPI, UPJ, TI, TJ)                                        \
    {                                                                          \
        const float u  = (UPI) - (UPJ);                                        \
        const float tg = (((TI) - (TJ)) > MARGIN) ? 1.0f : 0.0f;               \
        const float ax = fabsf(u);                                             \
        const float sp = __builtin_log2f(1.0f + __builtin_exp2f(-ax));         \
        const float bb = fmaxf(u, 0.0f) - u * tg + sp;                         \
        loss[nn] += (float)((mp >> (bit)) & 1u) * bb;                          \
    }

    #pragma unroll 4
    for (int c = 0; c < CHUNK; ++c) {
        const float4 pj0 = psc4[j * 512 + t];
        const float4 pj1 = psc4[j * 512 + t + 256];
        const float4 tj0 = tgt4[j * 512 + t];
        const float4 tj1 = tgt4[j * 512 + t + 256];
        const unsigned mj = pk[j * 256 + t];
        const unsigned mp = mi & mj;

        ELEM(0, 0, pi0.x, pj0.x, ti0.x, tj0.x);
        ELEM(1, 1, pi0.y, pj0.y, ti0.y, tj0.y);
        ELEM(2, 2, pi0.z, pj0.z, ti0.z, tj0.z);
        ELEM(3, 3, pi0.w, pj0.w, ti0.w, tj0.w);
        ELEM(0, 4, pi1.x, pj1.x, ti1.x, tj1.x);
        ELEM(1, 5, pi1.y, pj1.y, ti1.y, tj1.y);
        ELEM(2, 6, pi1.z, pj1.z, ti1.z, tj1.z);
        ELEM(3, 7, pi1.w, pj1.w, ti1.w, tj1.w);

        if (++j == B) {                 // row exhausted -> next row (uniform)
            ++i;
            if (i >= B - 1) break;      // past last row (only possible at c==15)
            j = i + 1;
            LOAD_I();
        }
    }
#undef ELEM
#undef LOAD_I

    // ---- block reduction: wave shuffle (64 lanes) -> LDS across 4 waves ----
    #pragma unroll
    for (int kk = 0; kk < 4; kk++) {
        #pragma unroll
        for (int off = 32; off > 0; off >>= 1)
            loss[kk] += __shfl_down(loss[kk], off, 64);
    }

    __shared__ float sred[4][4];
    const int wave = t >> 6;
    const int lane = t & 63;
    if (lane == 0) {
        #pragma unroll
        for (int kk = 0; kk < 4; kk++) sred[wave][kk] = loss[kk];
    }
    __syncthreads();

    if (t < 4) {
        const float v = sred[0][t] + sred[1][t] + sred[2][t] + sred[3][t];
        atomicAdd(&slab[(blockIdx.x & 31) * 4 + t], (double)v);
    }
}

// ---------------------------------------------------------------------------
// Finalize: total = (1/N) * sum_n where(cnt>0, ln2*loss2/(cnt+EPS), 0)
// ---------------------------------------------------------------------------
__global__ void finalize_kernel(const double* __restrict__ slab,
                                const double* __restrict__ cnt4,
                                float* __restrict__ out)
{
    double total = 0.0;
    #pragma unroll
    for (int n = 0; n < 4; n++) {
        double ls = 0.0;
        for (int s = 0; s < 32; ++s) ls += slab[s * 4 + n];
        const double cs = cnt4[n];
        total += (cs > 0.0) ? (LN2 * ls / (cs + 1e-8)) : 0.0;
    }
    out[0] = (float)(total / 4.0);
}

extern "C" void kernel_launch(void* const* d_in, const int* in_sizes, int n_in,
                              void* d_out, int out_size, void* d_ws, size_t ws_size,
                              hipStream_t stream)
{
    const float* preds   = (const float*)d_in[0];
    const float* targets = (const float*)d_in[1];
    const int*   masks   = (const int*)d_in[2];   // jnp.bool_ arrives as int32
    float* out = (float*)d_out;

    char* ws = (char*)d_ws;
    double*        slab = (double*)(ws + OFF_SLAB);
    double*        cnt4 = (double*)(ws + OFF_CNT);
    float*         psc  = (float*)(ws + OFF_PSC);
    unsigned char* pk   = (unsigned char*)(ws + OFF_PK);

    // zero accumulators every call (ws is poisoned once, never re-poisoned)
    (void)hipMemsetAsync(ws, 0, 2048, stream);

    prep_kernel<<<776, 256, 0, stream>>>(preds, masks, psc, pk, cnt4);
    pair_bce_kernel<<<NBLK, 256, 0, stream>>>(targets, psc, pk, slab);
    finalize_kernel<<<1, 1, 0, stream>>>(slab, cnt4, out);
}